// Round 5
// baseline (291.866 us; speedup 1.0000x reference)
//
#include <hip/hip_runtime.h>

// SE block: gap = mean(relation, spatial); bottle = relu(gap@W1^T + b1);
// gate = sigmoid(bottle@W2^T + b2); scale = float(int64(gate)); out = relation*scale.
// Shapes: relation [B=64, HEADS=16, 256, 256] fp32; W1 [4,16]; b1 [4]; W2 [16,4]; b2 [16].
//
// Single fused kernel: each block reduces its half-plane, signals via per-batch
// counter, spin-waits (acquire) for its batch row's 32 producers, computes the
// tiny MLP, then writes its half-plane. scale = float(int64(sigmoid)) is 0.0 or
// 1.0; when 0 the write phase emits zeros without re-reading `relation`.

#define NB 64
#define NHEADS 16
#define NPLANES (NB * NHEADS)               // 1024 planes
#define HW 65536                            // elements per plane
#define HW4 16384                           // float4s per plane
#define BLOCKS_PER_PLANE 2
#define CHUNK4 (HW4 / BLOCKS_PER_PLANE)     // 8192 float4s per block
#define NBLOCKS (NPLANES * BLOCKS_PER_PLANE)        // 2048 = 8 blocks/CU x 256 CUs
#define PRODUCERS_PER_BATCH (NHEADS * BLOCKS_PER_PLANE)  // 32

typedef float f32x4 __attribute__((ext_vector_type(4)));

// ---- init: zero per-plane accumulators and per-batch counters (ws not re-poisoned) ----
__global__ __launch_bounds__(256) void se_init_kernel(float* __restrict__ acc,
                                                      int* __restrict__ cnt) {
    const int i = threadIdx.x + blockIdx.x * 256;
    if (i < NPLANES) acc[i] = 0.0f;
    if (i < NB) cnt[i] = 0;
}

// ---- fused GAP + per-batch sync + MLP + broadcast multiply ----
__global__ __launch_bounds__(256, 8) void se_fused_kernel(const float* __restrict__ rel,
                                                          const float* __restrict__ W1,
                                                          const float* __restrict__ b1,
                                                          const float* __restrict__ W2,
                                                          const float* __restrict__ b2,
                                                          float* __restrict__ out,
                                                          float* __restrict__ acc,
                                                          int* __restrict__ cnt) {
    const int blk = blockIdx.x;
    const int p = blk >> 1;                 // plane id = b*16 + h
    const int q = blk & 1;                  // which half of the plane
    const int b = p >> 4;
    const int h = p & (NHEADS - 1);

    // ---- phase 1: reduce my half-plane ----
    const size_t base4 = (size_t)p * HW4 + (size_t)q * CHUNK4;
    const f32x4* __restrict__ src = (const f32x4*)rel + base4;
    float s = 0.0f;
    #pragma unroll 8
    for (int i = threadIdx.x; i < CHUNK4; i += 256) {
        f32x4 v = __builtin_nontemporal_load(src + i);
        s += (v.x + v.y) + (v.z + v.w);
    }
    #pragma unroll
    for (int off = 32; off > 0; off >>= 1)
        s += __shfl_down(s, off, 64);
    __shared__ float sm[4];
    if ((threadIdx.x & 63) == 0) sm[threadIdx.x >> 6] = s;
    __syncthreads();

    __shared__ float scale_sm;
    if (threadIdx.x == 0) {
        const float t = (sm[0] + sm[1]) + (sm[2] + sm[3]);
        // publish partial, then release-increment the batch counter
        __hip_atomic_fetch_add(acc + p, t, __ATOMIC_RELAXED, __HIP_MEMORY_SCOPE_AGENT);
        __hip_atomic_fetch_add(cnt + b, 1, __ATOMIC_RELEASE, __HIP_MEMORY_SCOPE_AGENT);
        // ---- phase 2: wait for my batch row's 32 producers ----
        while (__hip_atomic_load(cnt + b, __ATOMIC_ACQUIRE, __HIP_MEMORY_SCOPE_AGENT)
               < PRODUCERS_PER_BATCH)
            __builtin_amdgcn_s_sleep(2);
        // ---- phase 3: tiny SE MLP for my head ----
        float g[NHEADS];
        #pragma unroll
        for (int k = 0; k < NHEADS; ++k)
            g[k] = __hip_atomic_load(acc + (b * NHEADS + k), __ATOMIC_RELAXED,
                                     __HIP_MEMORY_SCOPE_AGENT) * (1.0f / (float)HW);
        float bot[4];
        #pragma unroll
        for (int c = 0; c < 4; ++c) {
            float a = b1[c];
            #pragma unroll
            for (int k = 0; k < NHEADS; ++k) a += g[k] * W1[c * NHEADS + k];
            bot[c] = fmaxf(a, 0.0f);
        }
        float a = b2[h];
        #pragma unroll
        for (int c = 0; c < 4; ++c) a += bot[c] * W2[h * 4 + c];
        const float gate = 1.0f / (1.0f + expf(-a));          // sigmoid
        scale_sm = (float)(long long)gate;                    // astype(int64) trunc
    }
    __syncthreads();
    const float sc = scale_sm;

    // ---- phase 4: write my half-plane ----
    f32x4* __restrict__ dst = (f32x4*)out + base4;
    if (sc == 0.0f) {
        const f32x4 z = {0.0f, 0.0f, 0.0f, 0.0f};
        #pragma unroll 8
        for (int i = threadIdx.x; i < CHUNK4; i += 256)
            __builtin_nontemporal_store(z, dst + i);
    } else {
        #pragma unroll 4
        for (int i = threadIdx.x; i < CHUNK4; i += 256) {
            f32x4 v = __builtin_nontemporal_load(src + i);
            v *= sc;
            __builtin_nontemporal_store(v, dst + i);
        }
    }
}

extern "C" void kernel_launch(void* const* d_in, const int* in_sizes, int n_in,
                              void* d_out, int out_size, void* d_ws, size_t ws_size,
                              hipStream_t stream) {
    const float* rel = (const float*)d_in[0];
    const float* W1  = (const float*)d_in[1];
    const float* b1  = (const float*)d_in[2];
    const float* W2  = (const float*)d_in[3];
    const float* b2  = (const float*)d_in[4];
    float* out = (float*)d_out;

    float* acc = (float*)d_ws;                  // NPLANES floats
    int*   cnt = (int*)((float*)d_ws + NPLANES);  // NB ints

    se_init_kernel<<<4, 256, 0, stream>>>(acc, cnt);
    se_fused_kernel<<<NBLOCKS, 256, 0, stream>>>(rel, W1, b1, W2, b2, out, acc, cnt);
}

// Round 7
// 218.381 us; speedup vs baseline: 1.3365x; 1.3365x over previous
//
#include <hip/hip_runtime.h>

// SE block: gap = mean(relation, spatial); bottle = relu(gap@W1^T + b1);
// gate = sigmoid(bottle@W2^T + b2); scale = float(int64(gate)); out = relation*scale.
// Shapes: relation [B=64, HEADS=16, 256, 256] fp32; W1 [4,16]; b1 [4]; W2 [16,4]; b2 [16].
//
// Fused single kernel with per-batch producer/consumer sync.
// R5 lesson: acquire-per-spin-iteration at agent scope = invalidate storm that
// throttled HBM to 1.3 TB/s. Now: relaxed spin + ONE acquire fence, s_sleep(16),
// per-line-padded counters, no float atomics (per-slot partials, deterministic).

#define NB 64
#define NHEADS 16
#define NPLANES (NB * NHEADS)               // 1024 planes
#define HW 65536                            // elements per plane
#define HW4 16384                           // float4s per plane
#define BLOCKS_PER_PLANE 2
#define CHUNK4 (HW4 / BLOCKS_PER_PLANE)     // 8192 float4s per block
#define NBLOCKS (NPLANES * BLOCKS_PER_PLANE)        // 2048 = 8 blocks/CU x 256 CUs
#define PRODUCERS_PER_BATCH (NHEADS * BLOCKS_PER_PLANE)  // 32
#define CNT_PAD 16                          // 64B per counter line

typedef float f32x4 __attribute__((ext_vector_type(4)));

// ---- init: zero partials and counters (ws is not re-poisoned between replays) ----
__global__ __launch_bounds__(256) void se_init_kernel(float* __restrict__ partial,
                                                      int* __restrict__ cnt) {
    const int i = threadIdx.x + blockIdx.x * 256;
    if (i < NBLOCKS) partial[i] = 0.0f;
    if (i < NB * CNT_PAD) cnt[i] = 0;
}

// ---- fused GAP + per-batch sync + MLP + broadcast multiply ----
__global__ __launch_bounds__(256, 8) void se_fused_kernel(const float* __restrict__ rel,
                                                          const float* __restrict__ W1,
                                                          const float* __restrict__ b1,
                                                          const float* __restrict__ W2,
                                                          const float* __restrict__ b2,
                                                          float* __restrict__ out,
                                                          float* __restrict__ partial,
                                                          int* __restrict__ cnt) {
    const int blk = blockIdx.x;
    const int p = blk >> 1;                 // plane id = b*16 + h
    const int q = blk & 1;                  // which half of the plane
    const int b = p >> 4;
    const int h = p & (NHEADS - 1);

    // ---- phase 1: reduce my half-plane ----
    const size_t base4 = (size_t)p * HW4 + (size_t)q * CHUNK4;
    const f32x4* __restrict__ src = (const f32x4*)rel + base4;
    float s = 0.0f;
    #pragma unroll 8
    for (int i = threadIdx.x; i < CHUNK4; i += 256) {
        f32x4 v = __builtin_nontemporal_load(src + i);
        s += (v.x + v.y) + (v.z + v.w);
    }
    #pragma unroll
    for (int off = 32; off > 0; off >>= 1)
        s += __shfl_down(s, off, 64);
    __shared__ float sm[4];
    if ((threadIdx.x & 63) == 0) sm[threadIdx.x >> 6] = s;
    __syncthreads();

    __shared__ float scale_sm;
    if (threadIdx.x == 0) {
        const float t = (sm[0] + sm[1]) + (sm[2] + sm[3]);
        // publish my partial (own slot -> deterministic), then release-count
        __hip_atomic_store(partial + blk, t, __ATOMIC_RELAXED, __HIP_MEMORY_SCOPE_AGENT);
        __hip_atomic_fetch_add(cnt + b * CNT_PAD, 1, __ATOMIC_RELEASE,
                               __HIP_MEMORY_SCOPE_AGENT);
        // ---- phase 2: RELAXED spin until my batch row's 32 producers are done ----
        while (__hip_atomic_load(cnt + b * CNT_PAD, __ATOMIC_RELAXED,
                                 __HIP_MEMORY_SCOPE_AGENT) < PRODUCERS_PER_BATCH)
            __builtin_amdgcn_s_sleep(16);   // ~1K cycles between probes
        __builtin_amdgcn_fence(__ATOMIC_ACQUIRE, "agent");  // one invalidate, not per-probe
        // ---- phase 3: tiny SE MLP for my head ----
        float g[NHEADS];
        #pragma unroll
        for (int k = 0; k < NHEADS; ++k) {
            const float p0 = __hip_atomic_load(partial + (b * NHEADS + k) * 2 + 0,
                                               __ATOMIC_RELAXED, __HIP_MEMORY_SCOPE_AGENT);
            const float p1 = __hip_atomic_load(partial + (b * NHEADS + k) * 2 + 1,
                                               __ATOMIC_RELAXED, __HIP_MEMORY_SCOPE_AGENT);
            g[k] = (p0 + p1) * (1.0f / (float)HW);
        }
        float bot[4];
        #pragma unroll
        for (int c = 0; c < 4; ++c) {
            float a = b1[c];
            #pragma unroll
            for (int k = 0; k < NHEADS; ++k) a += g[k] * W1[c * NHEADS + k];
            bot[c] = fmaxf(a, 0.0f);
        }
        float a = b2[h];
        #pragma unroll
        for (int c = 0; c < 4; ++c) a += bot[c] * W2[h * 4 + c];
        const float gate = 1.0f / (1.0f + expf(-a));          // sigmoid
        scale_sm = (float)(long long)gate;                    // astype(int64) trunc
    }
    __syncthreads();
    const float sc = scale_sm;

    // ---- phase 4: write my half-plane ----
    f32x4* __restrict__ dst = (f32x4*)out + base4;
    if (sc == 0.0f) {
        const f32x4 z = {0.0f, 0.0f, 0.0f, 0.0f};
        #pragma unroll 8
        for (int i = threadIdx.x; i < CHUNK4; i += 256)
            __builtin_nontemporal_store(z, dst + i);
    } else {
        #pragma unroll 4
        for (int i = threadIdx.x; i < CHUNK4; i += 256) {
            f32x4 v = __builtin_nontemporal_load(src + i);
            v *= sc;
            __builtin_nontemporal_store(v, dst + i);
        }
    }
}

extern "C" void kernel_launch(void* const* d_in, const int* in_sizes, int n_in,
                              void* d_out, int out_size, void* d_ws, size_t ws_size,
                              hipStream_t stream) {
    const float* rel = (const float*)d_in[0];
    const float* W1  = (const float*)d_in[1];
    const float* b1  = (const float*)d_in[2];
    const float* W2  = (const float*)d_in[3];
    const float* b2  = (const float*)d_in[4];
    float* out = (float*)d_out;

    float* partial = (float*)d_ws;                     // NBLOCKS floats (8 KB)
    int*   cnt     = (int*)((float*)d_ws + NBLOCKS);   // NB*CNT_PAD ints (4 KB)

    se_init_kernel<<<(NBLOCKS + 255) / 256, 256, 0, stream>>>(partial, cnt);
    se_fused_kernel<<<NBLOCKS, 256, 0, stream>>>(rel, W1, b1, W2, b2, out, partial, cnt);
}

// Round 8
// 101.515 us; speedup vs baseline: 2.8751x; 2.1512x over previous
//
#include <hip/hip_runtime.h>

// SE block: gap = mean(relation, spatial); bottle = relu(gap@W1^T + b1);
// gate = sigmoid(bottle@W2^T + b2); scale = float(int64(gate)); out = relation*scale.
// Shapes: relation [B=64, HEADS=16, 256, 256] fp32; W1 [4,16]; b1 [4]; W2 [16,4]; b2 [16].
//
// Structure (R7 lesson: in-kernel cross-block sync costs 2-3x a dispatch boundary):
//   Pass A: speculative zero-write of `out` + GAP partial reduction, fused in one
//           streaming loop (read rel + write zeros concurrently, no barrier).
//   Pass B: per-plane tiny MLP from partials; only if scale != 0 (fp32 sigmoid
//           rounds to 1.0 only for pre-activation >= ~18) rewrite the plane.
//           For typical data scale==0 everywhere -> pass B is ~2 us, no traffic.

#define NB 64
#define NHEADS 16
#define NPLANES (NB * NHEADS)          // 1024 planes
#define HW 65536                       // elements per plane
#define HW4 16384                      // float4s per plane
#define BPP 2                          // pass-A blocks per plane
#define CHUNK4 (HW4 / BPP)             // 8192 float4s per pass-A block
#define NBLOCKS_A (NPLANES * BPP)      // 2048 = 8 blocks/CU

typedef float f32x4 __attribute__((ext_vector_type(4)));

// ---- Pass A: zero `out` speculatively + half-plane partial sums ----
__global__ __launch_bounds__(256) void se_passA_kernel(const float* __restrict__ rel,
                                                       float* __restrict__ out,
                                                       float* __restrict__ partial) {
    const int blk = blockIdx.x;                      // = p*BPP + q
    const size_t base4 = (size_t)blk * CHUNK4;
    const f32x4* __restrict__ src = (const f32x4*)rel + base4;
    f32x4* __restrict__ dst = (f32x4*)out + base4;
    const f32x4 z = {0.0f, 0.0f, 0.0f, 0.0f};
    float s = 0.0f;
    #pragma unroll 8
    for (int i = threadIdx.x; i < CHUNK4; i += 256) {
        f32x4 v = __builtin_nontemporal_load(src + i);
        __builtin_nontemporal_store(z, dst + i);     // overlap write stream with read
        s += (v.x + v.y) + (v.z + v.w);
    }
    #pragma unroll
    for (int off = 32; off > 0; off >>= 1)
        s += __shfl_down(s, off, 64);
    __shared__ float sm[4];
    if ((threadIdx.x & 63) == 0) sm[threadIdx.x >> 6] = s;
    __syncthreads();
    if (threadIdx.x == 0)
        partial[blk] = (sm[0] + sm[1]) + (sm[2] + sm[3]);   // own slot, written every call
}

// ---- Pass B: per-plane MLP; fixup rewrite only when scale != 0 ----
__global__ __launch_bounds__(256) void se_passB_kernel(const float* __restrict__ rel,
                                                       const float* __restrict__ partial,
                                                       const float* __restrict__ W1,
                                                       const float* __restrict__ b1,
                                                       const float* __restrict__ W2,
                                                       const float* __restrict__ b2,
                                                       float* __restrict__ out) {
    const int p = blockIdx.x;                        // plane id = b*16 + h
    const int b = p >> 4;
    const int h = p & (NHEADS - 1);

    __shared__ float scale_sm;
    if (threadIdx.x == 0) {
        float g[NHEADS];
        #pragma unroll
        for (int k = 0; k < NHEADS; ++k) {
            const float* pp = partial + (size_t)(b * NHEADS + k) * BPP;
            g[k] = (pp[0] + pp[1]) * (1.0f / (float)HW);
        }
        float bot[4];
        #pragma unroll
        for (int c = 0; c < 4; ++c) {
            float a = b1[c];
            #pragma unroll
            for (int k = 0; k < NHEADS; ++k) a += g[k] * W1[c * NHEADS + k];
            bot[c] = fmaxf(a, 0.0f);
        }
        float a = b2[h];
        #pragma unroll
        for (int c = 0; c < 4; ++c) a += bot[c] * W2[h * 4 + c];
        const float gate = 1.0f / (1.0f + expf(-a));          // sigmoid
        scale_sm = (float)(long long)gate;                    // astype(int64) trunc
    }
    __syncthreads();
    const float sc = scale_sm;
    if (sc == 0.0f) return;                          // out already zeroed by pass A

    // rare fixup path: rewrite this plane as rel * sc
    const size_t base4 = (size_t)p * HW4;
    const f32x4* __restrict__ src = (const f32x4*)rel + base4;
    f32x4* __restrict__ dst = (f32x4*)out + base4;
    #pragma unroll 4
    for (int i = threadIdx.x; i < HW4; i += 256) {
        f32x4 v = __builtin_nontemporal_load(src + i);
        v *= sc;
        __builtin_nontemporal_store(v, dst + i);
    }
}

extern "C" void kernel_launch(void* const* d_in, const int* in_sizes, int n_in,
                              void* d_out, int out_size, void* d_ws, size_t ws_size,
                              hipStream_t stream) {
    const float* rel = (const float*)d_in[0];
    const float* W1  = (const float*)d_in[1];
    const float* b1  = (const float*)d_in[2];
    const float* W2  = (const float*)d_in[3];
    const float* b2  = (const float*)d_in[4];
    float* out = (float*)d_out;

    float* partial = (float*)d_ws;                   // NBLOCKS_A floats (8 KB)

    se_passA_kernel<<<NBLOCKS_A, 256, 0, stream>>>(rel, out, partial);
    se_passB_kernel<<<NPLANES, 256, 0, stream>>>(rel, partial, W1, b1, W2, b2, out);
}

// Round 9
// 94.267 us; speedup vs baseline: 3.0962x; 1.0769x over previous
//
#include <hip/hip_runtime.h>

// SE block: gap = mean(relation, spatial); bottle = relu(gap@W1^T + b1);
// gate = sigmoid(bottle@W2^T + b2); scale = float(int64(gate)); out = relation*scale.
// Shapes: relation [B=64, HEADS=16, 256, 256] fp32; W1 [4,16]; b1 [4]; W2 [16,4]; b2 [16].
//
// R3 structure (best: pure-read phase then pure-write phase; mixed streams and
// in-kernel sync both measured slower). R9 change: GAP uses TEMPORAL loads so
// rel (268 MB ~ L3 size) stays Infinity-Cache-resident across graph replays
// (R7 counters: FETCH 131 MB < 268 MB even with nt loads -> retention is real).
// Write kernel keeps nontemporal stores: out is never read.

#define NB 64
#define NHEADS 16
#define NPLANES (NB * NHEADS)     // 1024 planes
#define HW 65536                  // elements per plane
#define HW4 16384                 // float4s per plane
#define GAP_THREADS 512           // 8 waves/block, 1024 blocks -> 4 blocks/CU
#define MUL_CHUNKS 8              // blocks per plane in multiply kernel
#define CHUNK4 (HW4 / MUL_CHUNKS) // 2048 float4s per block

typedef float f32x4 __attribute__((ext_vector_type(4)));

// ---------------- Kernel 1: per-plane global average pool (temporal loads) ----------------
__global__ __launch_bounds__(GAP_THREADS) void se_gap_kernel(const float* __restrict__ rel,
                                                             float* __restrict__ gap) {
    const int p = blockIdx.x;                       // plane id = b*16 + h
    const f32x4* __restrict__ src = (const f32x4*)(rel + (size_t)p * HW);
    float s = 0.0f;
    #pragma unroll 4
    for (int i = threadIdx.x; i < HW4; i += GAP_THREADS) {
        f32x4 v = src[i];                           // temporal: allocate in L3 for next replay
        s += (v.x + v.y) + (v.z + v.w);
    }
    #pragma unroll
    for (int off = 32; off > 0; off >>= 1)
        s += __shfl_down(s, off, 64);
    __shared__ float ws[GAP_THREADS / 64];
    const int wave = threadIdx.x >> 6;
    if ((threadIdx.x & 63) == 0) ws[wave] = s;
    __syncthreads();
    if (threadIdx.x == 0) {
        float t = 0.0f;
        #pragma unroll
        for (int w = 0; w < GAP_THREADS / 64; ++w) t += ws[w];
        gap[p] = t * (1.0f / (float)HW);
    }
}

// ------- Kernel 2: fused SE-MLP (block-uniform, scalarized) + broadcast multiply -------
__global__ __launch_bounds__(256) void se_mlp_mul_kernel(const float* __restrict__ rel,
                                                         const float* __restrict__ gap,
                                                         const float* __restrict__ W1,
                                                         const float* __restrict__ b1,
                                                         const float* __restrict__ W2,
                                                         const float* __restrict__ b2,
                                                         float* __restrict__ out) {
    const int p     = blockIdx.x >> 3;              // plane id = b*16 + h
    const int chunk = blockIdx.x & (MUL_CHUNKS - 1);
    const int b = p >> 4;
    const int h = p & (NHEADS - 1);

    // --- tiny SE MLP, all operands block-uniform -> scalar loads + uniform VALU ---
    float bot[4];
    #pragma unroll
    for (int c = 0; c < 4; ++c) {
        float acc = b1[c];
        #pragma unroll
        for (int k = 0; k < NHEADS; ++k) acc += gap[b * NHEADS + k] * W1[c * NHEADS + k];
        bot[c] = fmaxf(acc, 0.0f);
    }
    float acc = b2[h];
    #pragma unroll
    for (int c = 0; c < 4; ++c) acc += bot[c] * W2[h * 4 + c];
    const float gate = 1.0f / (1.0f + expf(-acc));            // sigmoid
    const float s = (float)(long long)gate;                   // astype(int64) trunc

    const size_t base4 = (size_t)p * HW4 + (size_t)chunk * CHUNK4;
    f32x4* __restrict__ dst = (f32x4*)out + base4;
    if (s == 0.0f) {
        // output exactly zero; skip reading relation entirely
        const f32x4 z = {0.0f, 0.0f, 0.0f, 0.0f};
        for (int i = threadIdx.x; i < CHUNK4; i += 256)
            __builtin_nontemporal_store(z, dst + i);
    } else {
        const f32x4* __restrict__ src = (const f32x4*)rel + base4;
        for (int i = threadIdx.x; i < CHUNK4; i += 256) {
            f32x4 v = src[i];
            v *= s;
            __builtin_nontemporal_store(v, dst + i);
        }
    }
}

extern "C" void kernel_launch(void* const* d_in, const int* in_sizes, int n_in,
                              void* d_out, int out_size, void* d_ws, size_t ws_size,
                              hipStream_t stream) {
    const float* rel = (const float*)d_in[0];
    const float* W1  = (const float*)d_in[1];
    const float* b1  = (const float*)d_in[2];
    const float* W2  = (const float*)d_in[3];
    const float* b2  = (const float*)d_in[4];
    float* out = (float*)d_out;

    float* gap = (float*)d_ws;                    // NPLANES floats

    se_gap_kernel<<<NPLANES, GAP_THREADS, 0, stream>>>(rel, gap);
    se_mlp_mul_kernel<<<NPLANES * MUL_CHUNKS, 256, 0, stream>>>(rel, gap, W1, b1, W2, b2, out);
}